// Round 3
// baseline (454.482 us; speedup 1.0000x reference)
//
#include <hip/hip_runtime.h>

// out[b,o,i,l] = white_table[o,i, x[b,i,o,l]]
// B=8, IN=64, OUT=64, L=2048, LUT=256
// One block per (o,i): stage the 256-entry LUT once, then process all 8
// batch rows (contiguous 8 KiB on both the read and write side).

#define BATCH   8
#define IN_CH   64
#define OUT_CH  64
#define LEN     2048
#define LUTN    256
#define BSTRIDE ((size_t)IN_CH * OUT_CH * LEN)   // elements per batch slice

typedef float vfloat4 __attribute__((ext_vector_type(4)));  // native vec for nontemporal builtin
typedef int   vint4   __attribute__((ext_vector_type(4)));

__global__ __launch_bounds__(256) void WhiteTranspose_28406913696445_kernel(
    const int* __restrict__ x,
    const float* __restrict__ table,
    float* __restrict__ out)
{
    __shared__ float lut[LUTN];

    const int o = blockIdx.x >> 6;          // 0..63
    const int i = blockIdx.x & (IN_CH - 1); // 0..63

    // Stage this (o,i) LUT row into LDS: 256 floats, one per thread. One
    // barrier for the whole block lifetime.
    lut[threadIdx.x] = table[(o * IN_CH + i) * LUTN + threadIdx.x];
    __syncthreads();

    const size_t xrow = ((size_t)i * OUT_CH + o) * LEN;   // x[b,i,o,:]
    const size_t orow = ((size_t)o * IN_CH + i) * LEN;    // out[b,o,i,:]

    // 8 batches x 2 chunks = 16 independent int4->float4 pipelines/thread.
    #pragma unroll
    for (int b = 0; b < BATCH; ++b) {
        const vint4* __restrict__ xin = (const vint4*)(x + xrow + b * BSTRIDE);
        vfloat4* __restrict__ dst     = (vfloat4*)(out + orow + b * BSTRIDE);
        #pragma unroll
        for (int it = 0; it < 2; ++it) {
            const int idx = threadIdx.x + it * 256;
            const vint4 v = xin[idx];
            vfloat4 r;
            r.x = lut[v.x];
            r.y = lut[v.y];
            r.z = lut[v.z];
            r.w = lut[v.w];
            __builtin_nontemporal_store(r, &dst[idx]);
        }
    }
}

extern "C" void kernel_launch(void* const* d_in, const int* in_sizes, int n_in,
                              void* d_out, int out_size, void* d_ws, size_t ws_size,
                              hipStream_t stream) {
    const int*   x     = (const int*)d_in[0];
    const float* table = (const float*)d_in[1];
    float*       out   = (float*)d_out;

    WhiteTranspose_28406913696445_kernel<<<OUT_CH * IN_CH, 256, 0, stream>>>(x, table, out);
}

// Round 4
// 450.055 us; speedup vs baseline: 1.0098x; 1.0098x over previous
//
#include <hip/hip_runtime.h>

// out[b,o,i,l] = white_table[o,i, x[b,i,o,l]]
// B=8, IN=64, OUT=64, L=2048, LUT=256
// Grid: (o,i) x 4 batch-segments = 16384 blocks. Each block stages the 1 KiB
// LUT row once, then each thread runs 4 independent int4->gather->float4
// pipelines with ALL loads issued before any consumption (explicit MLP).

#define BATCH   8
#define IN_CH   64
#define OUT_CH  64
#define LEN     2048
#define LUTN    256
#define BSTRIDE ((size_t)IN_CH * OUT_CH * LEN)   // elements per batch slice

typedef float vfloat4 __attribute__((ext_vector_type(4)));
typedef int   vint4   __attribute__((ext_vector_type(4)));

__global__ __launch_bounds__(256, 8) void WhiteTranspose_28406913696445_kernel(
    const int* __restrict__ x,
    const float* __restrict__ table,
    float* __restrict__ out)
{
    __shared__ float lut[LUTN];

    const int pair = blockIdx.x >> 2;            // (o,i) id, 0..4095
    const int seg  = blockIdx.x & 3;             // batch segment, 2 batches each
    const int o = pair >> 6;
    const int i = pair & (IN_CH - 1);

    lut[threadIdx.x] = table[(size_t)pair * LUTN + threadIdx.x];
    __syncthreads();

    const size_t xrow = ((size_t)i * OUT_CH + o) * LEN;   // x[b,i,o,:]
    const size_t orow = ((size_t)o * IN_CH + i) * LEN;    // out[b,o,i,:]
    const int b0 = seg * 2;

    // Source/dest chunk addresses: 2 batches x 2 half-rows per thread.
    const vint4* __restrict__ xin0 = (const vint4*)(x + xrow + (size_t)b0 * BSTRIDE);
    const vint4* __restrict__ xin1 = (const vint4*)(x + xrow + (size_t)(b0 + 1) * BSTRIDE);
    vfloat4* __restrict__ dst0 = (vfloat4*)(out + orow + (size_t)b0 * BSTRIDE);
    vfloat4* __restrict__ dst1 = (vfloat4*)(out + orow + (size_t)(b0 + 1) * BSTRIDE);

    const int t = threadIdx.x;

    // Phase 1: issue ALL four 16B loads back-to-back (4 outstanding/thread).
    vint4 v0 = xin0[t];
    vint4 v1 = xin0[t + 256];
    vint4 v2 = xin1[t];
    vint4 v3 = xin1[t + 256];

    // Phase 2: gather + store, oldest-load first (precise vmcnt waits).
    vfloat4 r;
    r.x = lut[v0.x]; r.y = lut[v0.y]; r.z = lut[v0.z]; r.w = lut[v0.w];
    __builtin_nontemporal_store(r, &dst0[t]);
    r.x = lut[v1.x]; r.y = lut[v1.y]; r.z = lut[v1.z]; r.w = lut[v1.w];
    __builtin_nontemporal_store(r, &dst0[t + 256]);
    r.x = lut[v2.x]; r.y = lut[v2.y]; r.z = lut[v2.z]; r.w = lut[v2.w];
    __builtin_nontemporal_store(r, &dst1[t]);
    r.x = lut[v3.x]; r.y = lut[v3.y]; r.z = lut[v3.z]; r.w = lut[v3.w];
    __builtin_nontemporal_store(r, &dst1[t + 256]);
}

extern "C" void kernel_launch(void* const* d_in, const int* in_sizes, int n_in,
                              void* d_out, int out_size, void* d_ws, size_t ws_size,
                              hipStream_t stream) {
    const int*   x     = (const int*)d_in[0];
    const float* table = (const float*)d_in[1];
    float*       out   = (float*)d_out;

    WhiteTranspose_28406913696445_kernel<<<OUT_CH * IN_CH * 4, 256, 0, stream>>>(x, table, out);
}